// Round 15
// baseline (1088.614 us; speedup 1.0000x reference)
//
#include <hip/hip_runtime.h>
#include <cstddef>

#define B_ 64
#define T_ 32
#define S_ 128
#define IN_ 1024
#define H_ 1024

typedef _Float16 f16x8 __attribute__((ext_vector_type(8)));
typedef float f32x4 __attribute__((ext_vector_type(4)));

__device__ __forceinline__ float sigmoidf_(float x) { return 1.0f / (1.0f + expf(-x)); }

__device__ __forceinline__ ushort f2h(float x) {
    return __builtin_bit_cast(ushort, (_Float16)x);
}
__device__ __forceinline__ float h2f(ushort h) {
    return (float)__builtin_bit_cast(_Float16, h);
}

// async global->LDS, 16B per lane; lds dest wave-uniform (HW adds lane*16).
__device__ __forceinline__ void gll16(const ushort* g, ushort* l) {
    __builtin_amdgcn_global_load_lds(
        (const __attribute__((address_space(1))) void*)g,
        (__attribute__((address_space(3))) void*)l,
        16, 0, 0);
}

// ---------------- fp16 big-GEMM (preamble): C = A @ B^T ----------------
// A,B fp16 single-plane. out: Cf -> fp32 (+bias), else Ch -> fp16.
// Optional z-batching via element strides Az/Bz/Cz. XCD swizzle when nwg%8==0.
template<int FM, int FN>
__global__ __launch_bounds__(256) void gemm_16(
    const ushort* __restrict__ A16, long lda,
    const ushort* __restrict__ B16, long ldb,
    int K, int N,
    float* __restrict__ Cf, ushort* __restrict__ Ch,
    const float* __restrict__ bias,
    long Az, long Bz, long Cz)
{
    constexpr int NSA = 4 * FM;
    constexpr int NSB = 4 * FN;
    constexpr int NST = NSA + NSB;
    __shared__ ushort lds[NST * 512];

    const long z = blockIdx.z;
    A16 += z * Az;
    B16 += z * Bz;
    if (Cf) Cf += z * Cz;
    if (Ch) Ch += z * Cz;

    int flat = blockIdx.y * gridDim.x + blockIdx.x;
    const int nwg = gridDim.x * gridDim.y;
    if ((nwg & 7) == 0) {
        const int q = nwg >> 3;
        flat = (flat & 7) * q + (flat >> 3);
    }
    const int bx = flat % gridDim.x;
    const int by = flat / gridDim.x;

    const int tid = threadIdx.x;
    const int lane = tid & 63, wv = tid >> 6;
    const int wm = wv >> 1, wn = wv & 1;
    const int m0 = by * (FM * 32), n0 = bx * (FN * 32);
    const int lr = lane & 15, lc = lane >> 4;

    f32x4 acc[FM][FN];
#pragma unroll
    for (int i = 0; i < FM; ++i)
#pragma unroll
        for (int j = 0; j < FN; ++j) acc[i][j] = (f32x4){0.f, 0.f, 0.f, 0.f};

    for (int k0 = 0; k0 < K; k0 += 64) {
#pragma unroll
        for (int q = 0; q < NST / 4; ++q) {
            const int si = wv * (NST / 4) + q;
            const ushort* P; long ld; int row0; int st;
            if (si < NSA) { P = A16; ld = lda; row0 = m0; st = si; }
            else          { P = B16; ld = ldb; row0 = n0; st = si - NSA; }
            const int row = ((st >> 1) << 4) + lr;
            const int kc = ((st & 1) << 5) + (lc << 3);
            gll16(P + (size_t)(row0 + row) * ld + k0 + kc, &lds[si * 512]);
        }
        __syncthreads();
#pragma unroll
        for (int ks = 0; ks < 2; ++ks) {
            f16x8 a[FM], b[FN];
#pragma unroll
            for (int i = 0; i < FM; ++i)
                a[i] = *(const f16x8*)&lds[((wm * FM + i) * 2 + ks) * 512 + lane * 8];
#pragma unroll
            for (int j = 0; j < FN; ++j)
                b[j] = *(const f16x8*)&lds[(NSA + (wn * FN + j) * 2 + ks) * 512 + lane * 8];
#pragma unroll
            for (int i = 0; i < FM; ++i)
#pragma unroll
                for (int j = 0; j < FN; ++j)
                    acc[i][j] = __builtin_amdgcn_mfma_f32_16x16x32_f16(a[i], b[j], acc[i][j], 0, 0, 0);
        }
        __syncthreads();
    }

    const int fr = lane & 15, fc = lane >> 4;
#pragma unroll
    for (int i = 0; i < FM; ++i)
#pragma unroll
        for (int j = 0; j < FN; ++j) {
            const int mb = m0 + wm * FM * 16 + i * 16 + fc * 4;
            const int nb = n0 + wn * FN * 16 + j * 16 + fr;
            const float bv = bias ? bias[nb] : 0.f;
#pragma unroll
            for (int r = 0; r < 4; ++r) {
                const float v = acc[i][j][r] + bv;
                const size_t o = (size_t)(mb + r) * N + nb;
                if (Cf) Cf[o] = v;
                else Ch[o] = f2h(v);
            }
        }
}

// ---------------- per-step kernels (round-13/14 proven) ----------------

// Issue for fp16 gates: 10 subtiles/iter: si 0-1 = hc16 (ks), 2-9 = Whh16 (gate,ks).
// Wave 0: si{0,1,2}, wave 1: {3,4,5}, wave 2: {6,7}, wave 3: {8,9}.
__device__ __forceinline__ void gc16_issue(
    const ushort* __restrict__ hc16, const ushort* __restrict__ Whh16,
    int jc, int mb, int wv, int lr, int lc, int k0, ushort* dst)
{
    const int base = (wv < 2) ? wv * 3 : 6 + (wv - 2) * 2;
    const int cnt  = (wv < 2) ? 3 : 2;
#pragma unroll
    for (int q = 0; q < 3; ++q) {
        if (q >= cnt) break;
        const int si = base + q;
        const ushort* P; size_t rowoff; int ks;
        if (si < 2) {
            P = hc16; ks = si;
            rowoff = (size_t)(mb * 16 + lr) * 1024;
        } else {
            P = Whh16;
            const int g = (si - 2) >> 1;
            ks = (si - 2) & 1;
            rowoff = (size_t)(g * 1024 + jc * 16 + lr) * 1024;
        }
        gll16(P + rowoff + k0 + ks * 32 + lc * 8, dst + si * 512);
    }
}

// K1: gates + LSTM cell, fp16 single-plane h and Whh (1-term MFMA).
// grid (64 colgrp, 4 batchgrp); wave g = gate g. 3-buffer pipeline, counted vmcnt.
__global__ __launch_bounds__(256) void gates_cell(
    const ushort* __restrict__ hc16, const ushort* __restrict__ Whh16,
    const float* __restrict__ xWt,
    float* __restrict__ c_buf, ushort* __restrict__ hy16)
{
    __shared__ ushort lds[3][5120];    // 30 KB
    __shared__ float gl[1024];         // 4 KB
    const int jc = blockIdx.x;
    const int mb = blockIdx.y;
    const int tid = threadIdx.x, lane = tid & 63, wv = tid >> 6;
    const int lr = lane & 15, lc = lane >> 4;

    f32x4 acc = (f32x4){0.f, 0.f, 0.f, 0.f};

    gc16_issue(hc16, Whh16, jc, mb, wv, lr, lc, 0, &lds[0][0]);
#pragma unroll
    for (int it = 0; it < 16; ++it) {
        if (it < 15) {
            gc16_issue(hc16, Whh16, jc, mb, wv, lr, lc,
                       (it + 1) * 64, &lds[(it + 1) % 3][0]);
            if (wv < 2) asm volatile("s_waitcnt vmcnt(3)" ::: "memory");
            else        asm volatile("s_waitcnt vmcnt(2)" ::: "memory");
        } else {
            asm volatile("s_waitcnt vmcnt(0)" ::: "memory");
        }
        __builtin_amdgcn_s_barrier();
        __builtin_amdgcn_sched_barrier(0);
        const ushort* L = &lds[it % 3][0];
#pragma unroll
        for (int ks = 0; ks < 2; ++ks) {
            f16x8 a = *(const f16x8*)&L[ks * 512 + lane * 8];
            f16x8 b = *(const f16x8*)&L[(2 + wv * 2 + ks) * 512 + lane * 8];
            acc = __builtin_amdgcn_mfma_f32_16x16x32_f16(a, b, acc, 0, 0, 0);
        }
    }

    const int fr = lane & 15, fc = lane >> 4;
#pragma unroll
    for (int r = 0; r < 4; ++r)
        gl[wv * 256 + (fc * 4 + r) * 16 + fr] = acc[r];
    __syncthreads();

    const int bl_ = tid >> 4, cl = tid & 15;
    const int b = mb * 16 + bl_, col = jc * 16 + cl;
    const float* xw = xWt + (size_t)b * T_ * 4096;
    const float gi = gl[bl_ * 16 + cl]        + xw[col];
    const float gf = gl[256 + bl_ * 16 + cl]  + xw[1024 + col];
    const float gg = gl[512 + bl_ * 16 + cl]  + xw[2048 + col];
    const float go = gl[768 + bl_ * 16 + cl]  + xw[3072 + col];
    const int idx = b * 1024 + col;
    const float cn = sigmoidf_(gf) * c_buf[idx] + sigmoidf_(gi) * tanhf(gg);
    c_buf[idx] = cn;
    const float h = sigmoidf_(go) * tanhf(cn);
    hy16[idx] = f2h(h);
}

// K2: raw scores from fp16 E and fp16 hy. grid (64 b, 4 sgroup of 32).
__global__ __launch_bounds__(256) void scores_k(
    const ushort* __restrict__ E,
    const ushort* __restrict__ hy16,
    const float* __restrict__ mask, float* __restrict__ sc_raw)
{
    const int b = blockIdx.x, sg = blockIdx.y;
    const int tid = threadIdx.x, lane = tid & 63, wv = tid >> 6;
    __shared__ alignas(16) float sinp[IN_];
#pragma unroll
    for (int i = 0; i < 4; ++i) {
        const int j = tid + i * 256;
        sinp[j] = h2f(hy16[b * 1024 + j]);
    }
    __syncthreads();
#pragma unroll
    for (int r = 0; r < 8; ++r) {
        const int s = sg * 32 + wv * 8 + r;
        const ushort* row = E + ((size_t)b * S_ + s) * 1024;
        float sum = 0.f;
#pragma unroll
        for (int it = 0; it < 2; ++it) {
            const int e = it * 512 + lane * 8;
            const uint4 v = *(const uint4*)(row + e);
            const float4 w0 = *(const float4*)&sinp[e];
            const float4 w1 = *(const float4*)&sinp[e + 4];
            sum += h2f(v.x & 0xffff) * w0.x + h2f(v.x >> 16) * w0.y
                 + h2f(v.y & 0xffff) * w0.z + h2f(v.y >> 16) * w0.w
                 + h2f(v.z & 0xffff) * w1.x + h2f(v.z >> 16) * w1.y
                 + h2f(v.w & 0xffff) * w1.z + h2f(v.w >> 16) * w1.w;
        }
#pragma unroll
        for (int off = 32; off > 0; off >>= 1) sum += __shfl_xor(sum, off);
        if (lane == 0)
            sc_raw[b * S_ + s] = sum - (1.0f - mask[(size_t)b * S_ + s]) * 100000.0f;
    }
}

// outg staging (fp16, 1-term): 4 subtiles/iter: hy ks0/ks1, Woi ks0/ks1.
__device__ __forceinline__ void og16_issue(
    const ushort* __restrict__ hy16, const ushort* __restrict__ Woi16,
    size_t arow, size_t brow, int kb, int it, int lc, ushort* dst)
{
    const int k0 = kb + it * 64 + lc * 8;
    gll16(hy16 + arow + k0,        dst);
    gll16(hy16 + arow + k0 + 32,   dst + 512);
    gll16(Woi16 + brow + k0,       dst + 1024);
    gll16(Woi16 + brow + k0 + 32,  dst + 1536);
}

// K3: out = tanh( softmax(sc) @ Gt + hy @ Woi^T ). grid (64 colgrp, 4 batchgrp).
// G-part: fp16 Gt stream. MFMA part: fp16 1-term, wave-private K-split dbuf.
__global__ __launch_bounds__(256) void outg_k(
    const float* __restrict__ sc_raw,
    const ushort* __restrict__ Gt16,
    const ushort* __restrict__ hy16, const ushort* __restrict__ Woi16,
    float* __restrict__ outp, ushort* __restrict__ hc16)
{
    __shared__ ushort st[4][2][2048];   // 32 KB
    __shared__ float aS[16][128];       // 8 KB
    __shared__ float red[1024];         // 4 KB
    const int nc = blockIdx.x, mb = blockIdx.y;
    const int tid = threadIdx.x, lane = tid & 63, wv = tid >> 6;
    const int lr = lane & 15, lc = lane >> 4;
    const int kb = wv * 256;
    const size_t arow = (size_t)(mb * 16 + lr) * 1024;
    const size_t brow = (size_t)(nc * 16 + lr) * 1024;
    ushort* stw = &st[wv][0][0];

    og16_issue(hy16, Woi16, arow, brow, kb, 0, lc, stw);

    // softmax for this block's 16 batches (16 lanes per batch, in-wave)
    const int bl_ = tid >> 4, tl = tid & 15;
    const int b = mb * 16 + bl_;
    float v[8], mx = -3.4e38f;
#pragma unroll
    for (int i = 0; i < 8; ++i) {
        v[i] = sc_raw[b * S_ + tl * 8 + i];
        mx = fmaxf(mx, v[i]);
    }
#pragma unroll
    for (int off = 1; off < 16; off <<= 1) mx = fmaxf(mx, __shfl_xor(mx, off));
    float sm = 0.f;
#pragma unroll
    for (int i = 0; i < 8; ++i) { v[i] = expf(v[i] - mx); sm += v[i]; }
#pragma unroll
    for (int off = 1; off < 16; off <<= 1) sm += __shfl_xor(sm, off);
    const float inv = 1.0f / sm;
#pragma unroll
    for (int i = 0; i < 8; ++i) aS[bl_][tl * 8 + i] = v[i] * inv;
    asm volatile("s_waitcnt lgkmcnt(0)" ::: "memory");

    // G part: a @ Gt[b][col][:]  (Gt fp16 single plane)
    const int c = nc * 16 + tl;
    const ushort* gt = Gt16 + ((size_t)b * 1024 + c) * 128;
    float accg = 0.f;
#pragma unroll
    for (int i = 0; i < 16; ++i) {
        const uint4 g4 = *(const uint4*)(gt + i * 8);
        const float* a = &aS[bl_][i * 8];
        accg += a[0] * h2f(g4.x & 0xffff) + a[1] * h2f(g4.x >> 16)
              + a[2] * h2f(g4.y & 0xffff) + a[3] * h2f(g4.y >> 16)
              + a[4] * h2f(g4.z & 0xffff) + a[5] * h2f(g4.z >> 16)
              + a[6] * h2f(g4.w & 0xffff) + a[7] * h2f(g4.w >> 16);
    }

    // MFMA part: hy @ Woi^T (fp16 1-term), wave-private K slice, dbuf counted vmcnt
    asm volatile("s_waitcnt vmcnt(0)" ::: "memory");
    f32x4 acc = (f32x4){0.f, 0.f, 0.f, 0.f};
#pragma unroll
    for (int it = 0; it < 4; ++it) {
        if (it < 3) {
            og16_issue(hy16, Woi16, arow, brow, kb, it + 1, lc,
                       stw + ((it + 1) & 1) * 2048);
            asm volatile("s_waitcnt vmcnt(4)" ::: "memory");
        } else {
            asm volatile("s_waitcnt vmcnt(0)" ::: "memory");
        }
        __builtin_amdgcn_sched_barrier(0);
        const ushort* W = stw + (it & 1) * 2048;
#pragma unroll
        for (int ks = 0; ks < 2; ++ks) {
            f16x8 a = *(const f16x8*)&W[ks * 512 + lane * 8];
            f16x8 bb = *(const f16x8*)&W[(2 + ks) * 512 + lane * 8];
            acc = __builtin_amdgcn_mfma_f32_16x16x32_f16(a, bb, acc, 0, 0, 0);
        }
    }

    const int fc = lane >> 4, fr = lane & 15;
#pragma unroll
    for (int r = 0; r < 4; ++r)
        red[wv * 256 + (fc * 4 + r) * 16 + fr] = acc[r];
    __syncthreads();

    float o = accg + red[bl_ * 16 + tl] + red[256 + bl_ * 16 + tl]
            + red[512 + bl_ * 16 + tl] + red[768 + bl_ * 16 + tl];
    o = tanhf(o);
    outp[(size_t)b * T_ * 1024 + c] = o;
    hc16[b * 1024 + c] = f2h(o);
}

// ---------------- conversion / misc ----------------
__global__ __launch_bounds__(256) void cvt1h_k(
    const float* __restrict__ in, ushort* __restrict__ out, int n4)
{
    const int i = blockIdx.x * 256 + threadIdx.x;
    if (i >= n4) return;
    const float4 v = ((const float4*)in)[i];
    ushort4 h;
    h.x = f2h(v.x); h.y = f2h(v.y); h.z = f2h(v.z); h.w = f2h(v.w);
    ((ushort4*)out)[i] = h;
}

// strided fp16 cvt: row r has rowlen4 float4s read from in + r*instride4 (float4 units)
__global__ __launch_bounds__(256) void cvt1hs_k(
    const float* __restrict__ in, long instride4, int rowlen4,
    ushort* __restrict__ out, int n4)
{
    const int i = blockIdx.x * 256 + threadIdx.x;
    if (i >= n4) return;
    const int r = i / rowlen4, c = i - r * rowlen4;
    const float4 v = ((const float4*)in)[(size_t)r * instride4 + c];
    ushort4 h;
    h.x = f2h(v.x); h.y = f2h(v.y); h.z = f2h(v.z); h.w = f2h(v.w);
    ((ushort4*)out)[i] = h;
}

__global__ void transpose_k(const float* __restrict__ in, float* __restrict__ out)
{
    __shared__ float tile[32][33];
    const int bx = blockIdx.x * 32, by = blockIdx.y * 32;
    const int tx = threadIdx.x, ty = threadIdx.y;   // (32,8)
#pragma unroll
    for (int i = 0; i < 32; i += 8)
        tile[ty + i][tx] = in[(size_t)(by + ty + i) * 1024 + bx + tx];
    __syncthreads();
#pragma unroll
    for (int i = 0; i < 32; i += 8)
        out[(size_t)(bx + ty + i) * 1024 + by + tx] = tile[tx][ty + i];
}

__global__ __launch_bounds__(256) void add_bias_k(
    const float* __restrict__ a, const float* __restrict__ b, float* __restrict__ o, int n)
{
    const int i = blockIdx.x * 256 + threadIdx.x;
    if (i < n) o[i] = a[i] + b[i];
}

__global__ __launch_bounds__(256) void finalize_k(
    const float* __restrict__ out_full, const float* __restrict__ c_buf,
    float* __restrict__ hT, float* __restrict__ cT)
{
    const int idx = blockIdx.x * 256 + threadIdx.x;
    const int b = idx >> 10, j = idx & 1023;
    hT[idx] = out_full[(size_t)b * T_ * H_ + (size_t)(T_ - 1) * H_ + j];
    cT[idx] = c_buf[idx];
}

extern "C" void kernel_launch(void* const* d_in, const int* in_sizes, int n_in,
                              void* d_out, int out_size, void* d_ws, size_t ws_size,
                              hipStream_t stream) {
    const float* target = (const float*)d_in[0];
    const float* h0     = (const float*)d_in[1];
    const float* c0     = (const float*)d_in[2];
    const float* ctx    = (const float*)d_in[3];
    const float* mask   = (const float*)d_in[4];
    const float* W_ih   = (const float*)d_in[5];
    const float* b_ih   = (const float*)d_in[6];
    const float* W_hh   = (const float*)d_in[7];
    const float* b_hh   = (const float*)d_in[8];
    const float* W_in   = (const float*)d_in[9];
    const float* W_ctx  = (const float*)d_in[10];
    const float* W_out  = (const float*)d_in[11];

    float* out = (float*)d_out;
    float* hT  = out + (size_t)B_ * T_ * H_;
    float* cT  = hT + (size_t)B_ * H_;

    // ---- workspace layout ----
    char* p = (char*)d_ws;
    ushort* E_h   = (ushort*)p;            p += 8388608ull * 2;    // 16.78 MB fp16
    float*  xW    = (float*)p;             p += 8388608ull * 4;    // 33.55 MB
    ushort* Gt16  = (ushort*)p;            p += 8388608ull * 2;    // 16.78 MB fp16
    ushort* Whh16 = (ushort*)p;            p += 4194304ull * 2;    // 8.39 MB fp16
    ushort* Woi16 = (ushort*)p;            p += 1048576ull * 2;    // 2.10 MB fp16
    float*  bias_sum = (float*)p;          p += 4096ull * 4;
    float*  c_buf = (float*)p;             p += 65536ull * 4;
    ushort* hy16  = (ushort*)p;            p += 65536ull * 2;
    ushort* hc16  = (ushort*)p;            p += 65536ull * 2;
    float*  sc_raw = (float*)p;            p += 8192ull * 4;
    ushort* dcslot = (ushort*)p;           p += 8388608ull * 2;    // dc16, later tgt16
    ushort* trans  = (ushort*)p;           p += 20971520ull * 2;   // 41.9 MB transient

    ushort* dc16   = dcslot;
    // transient phase A: ctx fp16 + W_ctx fp16
    ushort* ctx16  = trans;                            // 16,777,216
    ushort* Wctx16 = trans + 16777216;                 // 2,097,152
    // transient phase B: WinT_f + WinT16 + Wo1_16 + Wo2_16
    float*  WinT_f = (float*)trans;                    // 1,048,576 f (2,097,152 u-slots)
    ushort* WinT16 = trans + 2097152;
    ushort* Wo1_16 = trans + 3145728;
    ushort* Wo2_16 = trans + 4194304;
    // transient phase C: tgt16 (dc slot) + Wih16 (trans)
    ushort* tgt16  = dcslot;
    ushort* Wih16  = trans;

    // ---- preamble ----
    add_bias_k<<<16, 256, 0, stream>>>(b_ih, b_hh, bias_sum, 4 * H_);
    cvt1h_k<<<4096, 256, 0, stream>>>(W_hh, Whh16, 1048576);

    // dc16 = ctx @ W_ctx^T (fp16), 256x128 tile
    cvt1h_k<<<16384, 256, 0, stream>>>(ctx, ctx16, 4194304);
    cvt1h_k<<<2048, 256, 0, stream>>>(W_ctx, Wctx16, 524288);
    gemm_16<8, 4><<<dim3(8, 32), 256, 0, stream>>>(
        ctx16, 2048, Wctx16, 2048, 2048, 1024,
        nullptr, dc16, nullptr, 0, 0, 0);

    // WinT, Woi16 = Wo2@W_in, E = dc@W_in (fp16), Gt[b] = Wo1 @ dc[b]^T (fp16)
    transpose_k<<<dim3(32, 32), dim3(32, 8), 0, stream>>>(W_in, WinT_f);
    cvt1h_k<<<1024, 256, 0, stream>>>(WinT_f, WinT16, 262144);
    cvt1hs_k<<<1024, 256, 0, stream>>>(W_out, 512, 256, Wo1_16, 262144);
    cvt1hs_k<<<1024, 256, 0, stream>>>(W_out + 1024, 512, 256, Wo2_16, 262144);
    gemm_16<4, 4><<<dim3(8, 8), 256, 0, stream>>>(
        Wo2_16, 1024, WinT16, 1024, 1024, 1024,
        nullptr, Woi16, nullptr, 0, 0, 0);
    gemm_16<8, 4><<<dim3(8, 32), 256, 0, stream>>>(
        dc16, 1024, WinT16, 1024, 1024, 1024,
        nullptr, E_h, nullptr, 0, 0, 0);
    gemm_16<8, 4><<<dim3(1, 4, 64), 256, 0, stream>>>(
        Wo1_16, 1024, dc16, 1024, 1024, 128,
        nullptr, Gt16, nullptr, 0, 131072, 131072);

    // xW = target @ W_ih^T + bias (dc dead now), 256x128 tile
    cvt1h_k<<<2048, 256, 0, stream>>>(target, tgt16, 524288);
    cvt1h_k<<<4096, 256, 0, stream>>>(W_ih, Wih16, 1048576);
    gemm_16<8, 4><<<dim3(32, 8), 256, 0, stream>>>(
        tgt16, 1024, Wih16, 1024, 1024, 4096,
        xW, nullptr, bias_sum, 0, 0, 0);

    // loop state
    cvt1h_k<<<64, 256, 0, stream>>>(h0, hc16, 16384);
    hipMemcpyAsync(c_buf, c0, sizeof(float) * B_ * H_, hipMemcpyDeviceToDevice, stream);

    for (int t = 0; t < T_; ++t) {
        gates_cell<<<dim3(64, 4), 256, 0, stream>>>(
            hc16, Whh16, xW + (size_t)t * 4096, c_buf, hy16);
        scores_k<<<dim3(64, 4), 256, 0, stream>>>(E_h, hy16, mask, sc_raw);
        outg_k<<<dim3(64, 4), 256, 0, stream>>>(
            sc_raw, Gt16, hy16, Woi16,
            out + (size_t)t * H_, hc16);
    }

    finalize_k<<<256, 256, 0, stream>>>(out, c_buf, hT, cT);
}

// Round 16
// 1042.547 us; speedup vs baseline: 1.0442x; 1.0442x over previous
//
#include <hip/hip_runtime.h>
#include <cstddef>

#define B_ 64
#define T_ 32
#define S_ 128
#define IN_ 1024
#define H_ 1024

typedef _Float16 f16x8 __attribute__((ext_vector_type(8)));
typedef float f32x4 __attribute__((ext_vector_type(4)));

__device__ __forceinline__ float sigmoidf_(float x) { return 1.0f / (1.0f + expf(-x)); }

__device__ __forceinline__ ushort f2h(float x) {
    return __builtin_bit_cast(ushort, (_Float16)x);
}
__device__ __forceinline__ float h2f(ushort h) {
    return (float)__builtin_bit_cast(_Float16, h);
}

// async global->LDS, 16B per lane; lds dest wave-uniform (HW adds lane*16).
__device__ __forceinline__ void gll16(const ushort* g, ushort* l) {
    __builtin_amdgcn_global_load_lds(
        (const __attribute__((address_space(1))) void*)g,
        (__attribute__((address_space(3))) void*)l,
        16, 0, 0);
}

// ---------------- fp16 big-GEMM (preamble): C = A @ B^T ----------------
// A,B fp16 single-plane. out: Cf -> fp32 (+bias), else Ch -> fp16.
// Optional z-batching via element strides Az/Bz/Cz. XCD swizzle when nwg%8==0.
template<int FM, int FN>
__global__ __launch_bounds__(256) void gemm_16(
    const ushort* __restrict__ A16, long lda,
    const ushort* __restrict__ B16, long ldb,
    int K, int N,
    float* __restrict__ Cf, ushort* __restrict__ Ch,
    const float* __restrict__ bias,
    long Az, long Bz, long Cz)
{
    constexpr int NSA = 4 * FM;
    constexpr int NSB = 4 * FN;
    constexpr int NST = NSA + NSB;
    __shared__ ushort lds[NST * 512];

    const long z = blockIdx.z;
    A16 += z * Az;
    B16 += z * Bz;
    if (Cf) Cf += z * Cz;
    if (Ch) Ch += z * Cz;

    int flat = blockIdx.y * gridDim.x + blockIdx.x;
    const int nwg = gridDim.x * gridDim.y;
    if ((nwg & 7) == 0) {
        const int q = nwg >> 3;
        flat = (flat & 7) * q + (flat >> 3);
    }
    const int bx = flat % gridDim.x;
    const int by = flat / gridDim.x;

    const int tid = threadIdx.x;
    const int lane = tid & 63, wv = tid >> 6;
    const int wm = wv >> 1, wn = wv & 1;
    const int m0 = by * (FM * 32), n0 = bx * (FN * 32);
    const int lr = lane & 15, lc = lane >> 4;

    f32x4 acc[FM][FN];
#pragma unroll
    for (int i = 0; i < FM; ++i)
#pragma unroll
        for (int j = 0; j < FN; ++j) acc[i][j] = (f32x4){0.f, 0.f, 0.f, 0.f};

    for (int k0 = 0; k0 < K; k0 += 64) {
#pragma unroll
        for (int q = 0; q < NST / 4; ++q) {
            const int si = wv * (NST / 4) + q;
            const ushort* P; long ld; int row0; int st;
            if (si < NSA) { P = A16; ld = lda; row0 = m0; st = si; }
            else          { P = B16; ld = ldb; row0 = n0; st = si - NSA; }
            const int row = ((st >> 1) << 4) + lr;
            const int kc = ((st & 1) << 5) + (lc << 3);
            gll16(P + (size_t)(row0 + row) * ld + k0 + kc, &lds[si * 512]);
        }
        __syncthreads();
#pragma unroll
        for (int ks = 0; ks < 2; ++ks) {
            f16x8 a[FM], b[FN];
#pragma unroll
            for (int i = 0; i < FM; ++i)
                a[i] = *(const f16x8*)&lds[((wm * FM + i) * 2 + ks) * 512 + lane * 8];
#pragma unroll
            for (int j = 0; j < FN; ++j)
                b[j] = *(const f16x8*)&lds[(NSA + (wn * FN + j) * 2 + ks) * 512 + lane * 8];
#pragma unroll
            for (int i = 0; i < FM; ++i)
#pragma unroll
                for (int j = 0; j < FN; ++j)
                    acc[i][j] = __builtin_amdgcn_mfma_f32_16x16x32_f16(a[i], b[j], acc[i][j], 0, 0, 0);
        }
        __syncthreads();
    }

    const int fr = lane & 15, fc = lane >> 4;
#pragma unroll
    for (int i = 0; i < FM; ++i)
#pragma unroll
        for (int j = 0; j < FN; ++j) {
            const int mb = m0 + wm * FM * 16 + i * 16 + fc * 4;
            const int nb = n0 + wn * FN * 16 + j * 16 + fr;
            const float bv = bias ? bias[nb] : 0.f;
#pragma unroll
            for (int r = 0; r < 4; ++r) {
                const float v = acc[i][j][r] + bv;
                const size_t o = (size_t)(mb + r) * N + nb;
                if (Cf) Cf[o] = v;
                else Ch[o] = f2h(v);
            }
        }
}

// ---------------- per-step kernels (round-13/14 proven) ----------------

// Issue for fp16 gates: 10 subtiles/iter: si 0-1 = hc16 (ks), 2-9 = Whh16 (gate,ks).
// Wave 0: si{0,1,2}, wave 1: {3,4,5}, wave 2: {6,7}, wave 3: {8,9}.
__device__ __forceinline__ void gc16_issue(
    const ushort* __restrict__ hc16, const ushort* __restrict__ Whh16,
    int jc, int mb, int wv, int lr, int lc, int k0, ushort* dst)
{
    const int base = (wv < 2) ? wv * 3 : 6 + (wv - 2) * 2;
    const int cnt  = (wv < 2) ? 3 : 2;
#pragma unroll
    for (int q = 0; q < 3; ++q) {
        if (q >= cnt) break;
        const int si = base + q;
        const ushort* P; size_t rowoff; int ks;
        if (si < 2) {
            P = hc16; ks = si;
            rowoff = (size_t)(mb * 16 + lr) * 1024;
        } else {
            P = Whh16;
            const int g = (si - 2) >> 1;
            ks = (si - 2) & 1;
            rowoff = (size_t)(g * 1024 + jc * 16 + lr) * 1024;
        }
        gll16(P + rowoff + k0 + ks * 32 + lc * 8, dst + si * 512);
    }
}

// K1: gates + LSTM cell, fp16 single-plane h and Whh (1-term MFMA).
// grid (64 colgrp, 4 batchgrp); wave g = gate g. 3-buffer pipeline, counted vmcnt.
__global__ __launch_bounds__(256) void gates_cell(
    const ushort* __restrict__ hc16, const ushort* __restrict__ Whh16,
    const float* __restrict__ xWt,
    float* __restrict__ c_buf, ushort* __restrict__ hy16)
{
    __shared__ ushort lds[3][5120];    // 30 KB
    __shared__ float gl[1024];         // 4 KB
    const int jc = blockIdx.x;
    const int mb = blockIdx.y;
    const int tid = threadIdx.x, lane = tid & 63, wv = tid >> 6;
    const int lr = lane & 15, lc = lane >> 4;

    f32x4 acc = (f32x4){0.f, 0.f, 0.f, 0.f};

    gc16_issue(hc16, Whh16, jc, mb, wv, lr, lc, 0, &lds[0][0]);
#pragma unroll
    for (int it = 0; it < 16; ++it) {
        if (it < 15) {
            gc16_issue(hc16, Whh16, jc, mb, wv, lr, lc,
                       (it + 1) * 64, &lds[(it + 1) % 3][0]);
            if (wv < 2) asm volatile("s_waitcnt vmcnt(3)" ::: "memory");
            else        asm volatile("s_waitcnt vmcnt(2)" ::: "memory");
        } else {
            asm volatile("s_waitcnt vmcnt(0)" ::: "memory");
        }
        __builtin_amdgcn_s_barrier();
        __builtin_amdgcn_sched_barrier(0);
        const ushort* L = &lds[it % 3][0];
#pragma unroll
        for (int ks = 0; ks < 2; ++ks) {
            f16x8 a = *(const f16x8*)&L[ks * 512 + lane * 8];
            f16x8 b = *(const f16x8*)&L[(2 + wv * 2 + ks) * 512 + lane * 8];
            acc = __builtin_amdgcn_mfma_f32_16x16x32_f16(a, b, acc, 0, 0, 0);
        }
    }

    const int fr = lane & 15, fc = lane >> 4;
#pragma unroll
    for (int r = 0; r < 4; ++r)
        gl[wv * 256 + (fc * 4 + r) * 16 + fr] = acc[r];
    __syncthreads();

    const int bl_ = tid >> 4, cl = tid & 15;
    const int b = mb * 16 + bl_, col = jc * 16 + cl;
    const float* xw = xWt + (size_t)b * T_ * 4096;
    const float gi = gl[bl_ * 16 + cl]        + xw[col];
    const float gf = gl[256 + bl_ * 16 + cl]  + xw[1024 + col];
    const float gg = gl[512 + bl_ * 16 + cl]  + xw[2048 + col];
    const float go = gl[768 + bl_ * 16 + cl]  + xw[3072 + col];
    const int idx = b * 1024 + col;
    const float cn = sigmoidf_(gf) * c_buf[idx] + sigmoidf_(gi) * tanhf(gg);
    c_buf[idx] = cn;
    const float h = sigmoidf_(go) * tanhf(cn);
    hy16[idx] = f2h(h);
}

// K2: raw scores from fp16 E and fp16 hy. grid (64 b, 4 sgroup of 32).
__global__ __launch_bounds__(256) void scores_k(
    const ushort* __restrict__ E,
    const ushort* __restrict__ hy16,
    const float* __restrict__ mask, float* __restrict__ sc_raw)
{
    const int b = blockIdx.x, sg = blockIdx.y;
    const int tid = threadIdx.x, lane = tid & 63, wv = tid >> 6;
    __shared__ alignas(16) float sinp[IN_];
#pragma unroll
    for (int i = 0; i < 4; ++i) {
        const int j = tid + i * 256;
        sinp[j] = h2f(hy16[b * 1024 + j]);
    }
    __syncthreads();
#pragma unroll
    for (int r = 0; r < 8; ++r) {
        const int s = sg * 32 + wv * 8 + r;
        const ushort* row = E + ((size_t)b * S_ + s) * 1024;
        float sum = 0.f;
#pragma unroll
        for (int it = 0; it < 2; ++it) {
            const int e = it * 512 + lane * 8;
            const uint4 v = *(const uint4*)(row + e);
            const float4 w0 = *(const float4*)&sinp[e];
            const float4 w1 = *(const float4*)&sinp[e + 4];
            sum += h2f(v.x & 0xffff) * w0.x + h2f(v.x >> 16) * w0.y
                 + h2f(v.y & 0xffff) * w0.z + h2f(v.y >> 16) * w0.w
                 + h2f(v.z & 0xffff) * w1.x + h2f(v.z >> 16) * w1.y
                 + h2f(v.w & 0xffff) * w1.z + h2f(v.w >> 16) * w1.w;
        }
#pragma unroll
        for (int off = 32; off > 0; off >>= 1) sum += __shfl_xor(sum, off);
        if (lane == 0)
            sc_raw[b * S_ + s] = sum - (1.0f - mask[(size_t)b * S_ + s]) * 100000.0f;
    }
}

// outg staging (fp16, 1-term): 4 subtiles/iter: hy ks0/ks1, Woi ks0/ks1.
__device__ __forceinline__ void og16_issue(
    const ushort* __restrict__ hy16, const ushort* __restrict__ Woi16,
    size_t arow, size_t brow, int kb, int it, int lc, ushort* dst)
{
    const int k0 = kb + it * 64 + lc * 8;
    gll16(hy16 + arow + k0,        dst);
    gll16(hy16 + arow + k0 + 32,   dst + 512);
    gll16(Woi16 + brow + k0,       dst + 1024);
    gll16(Woi16 + brow + k0 + 32,  dst + 1536);
}

// K3: out = tanh( softmax(sc) @ Gt + hy @ Woi^T ). grid (64 colgrp, 4 batchgrp).
// G-part: fp16 Gt stream. MFMA part: fp16 1-term, wave-private K-split dbuf.
__global__ __launch_bounds__(256) void outg_k(
    const float* __restrict__ sc_raw,
    const ushort* __restrict__ Gt16,
    const ushort* __restrict__ hy16, const ushort* __restrict__ Woi16,
    float* __restrict__ outp, ushort* __restrict__ hc16)
{
    __shared__ ushort st[4][2][2048];   // 32 KB
    __shared__ float aS[16][128];       // 8 KB
    __shared__ float red[1024];         // 4 KB
    const int nc = blockIdx.x, mb = blockIdx.y;
    const int tid = threadIdx.x, lane = tid & 63, wv = tid >> 6;
    const int lr = lane & 15, lc = lane >> 4;
    const int kb = wv * 256;
    const size_t arow = (size_t)(mb * 16 + lr) * 1024;
    const size_t brow = (size_t)(nc * 16 + lr) * 1024;
    ushort* stw = &st[wv][0][0];

    og16_issue(hy16, Woi16, arow, brow, kb, 0, lc, stw);

    // softmax for this block's 16 batches (16 lanes per batch, in-wave)
    const int bl_ = tid >> 4, tl = tid & 15;
    const int b = mb * 16 + bl_;
    float v[8], mx = -3.4e38f;
#pragma unroll
    for (int i = 0; i < 8; ++i) {
        v[i] = sc_raw[b * S_ + tl * 8 + i];
        mx = fmaxf(mx, v[i]);
    }
#pragma unroll
    for (int off = 1; off < 16; off <<= 1) mx = fmaxf(mx, __shfl_xor(mx, off));
    float sm = 0.f;
#pragma unroll
    for (int i = 0; i < 8; ++i) { v[i] = expf(v[i] - mx); sm += v[i]; }
#pragma unroll
    for (int off = 1; off < 16; off <<= 1) sm += __shfl_xor(sm, off);
    const float inv = 1.0f / sm;
#pragma unroll
    for (int i = 0; i < 8; ++i) aS[bl_][tl * 8 + i] = v[i] * inv;
    asm volatile("s_waitcnt lgkmcnt(0)" ::: "memory");

    // G part: a @ Gt[b][col][:]  (Gt fp16 single plane)
    const int c = nc * 16 + tl;
    const ushort* gt = Gt16 + ((size_t)b * 1024 + c) * 128;
    float accg = 0.f;
#pragma unroll
    for (int i = 0; i < 16; ++i) {
        const uint4 g4 = *(const uint4*)(gt + i * 8);
        const float* a = &aS[bl_][i * 8];
        accg += a[0] * h2f(g4.x & 0xffff) + a[1] * h2f(g4.x >> 16)
              + a[2] * h2f(g4.y & 0xffff) + a[3] * h2f(g4.y >> 16)
              + a[4] * h2f(g4.z & 0xffff) + a[5] * h2f(g4.z >> 16)
              + a[6] * h2f(g4.w & 0xffff) + a[7] * h2f(g4.w >> 16);
    }

    // MFMA part: hy @ Woi^T (fp16 1-term), wave-private K slice, dbuf counted vmcnt
    asm volatile("s_waitcnt vmcnt(0)" ::: "memory");
    f32x4 acc = (f32x4){0.f, 0.f, 0.f, 0.f};
#pragma unroll
    for (int it = 0; it < 4; ++it) {
        if (it < 3) {
            og16_issue(hy16, Woi16, arow, brow, kb, it + 1, lc,
                       stw + ((it + 1) & 1) * 2048);
            asm volatile("s_waitcnt vmcnt(4)" ::: "memory");
        } else {
            asm volatile("s_waitcnt vmcnt(0)" ::: "memory");
        }
        __builtin_amdgcn_sched_barrier(0);
        const ushort* W = stw + (it & 1) * 2048;
#pragma unroll
        for (int ks = 0; ks < 2; ++ks) {
            f16x8 a = *(const f16x8*)&W[ks * 512 + lane * 8];
            f16x8 bb = *(const f16x8*)&W[(2 + ks) * 512 + lane * 8];
            acc = __builtin_amdgcn_mfma_f32_16x16x32_f16(a, bb, acc, 0, 0, 0);
        }
    }

    const int fc = lane >> 4, fr = lane & 15;
#pragma unroll
    for (int r = 0; r < 4; ++r)
        red[wv * 256 + (fc * 4 + r) * 16 + fr] = acc[r];
    __syncthreads();

    float o = accg + red[bl_ * 16 + tl] + red[256 + bl_ * 16 + tl]
            + red[512 + bl_ * 16 + tl] + red[768 + bl_ * 16 + tl];
    o = tanhf(o);
    outp[(size_t)b * T_ * 1024 + c] = o;
    hc16[b * 1024 + c] = f2h(o);
}

// ---------------- conversion / misc ----------------
__global__ __launch_bounds__(256) void cvt1h_k(
    const float* __restrict__ in, ushort* __restrict__ out, int n4)
{
    const int i = blockIdx.x * 256 + threadIdx.x;
    if (i >= n4) return;
    const float4 v = ((const float4*)in)[i];
    ushort4 h;
    h.x = f2h(v.x); h.y = f2h(v.y); h.z = f2h(v.z); h.w = f2h(v.w);
    ((ushort4*)out)[i] = h;
}

// strided fp16 cvt: row r has rowlen4 float4s read from in + r*instride4 (float4 units)
__global__ __launch_bounds__(256) void cvt1hs_k(
    const float* __restrict__ in, long instride4, int rowlen4,
    ushort* __restrict__ out, int n4)
{
    const int i = blockIdx.x * 256 + threadIdx.x;
    if (i >= n4) return;
    const int r = i / rowlen4, c = i - r * rowlen4;
    const float4 v = ((const float4*)in)[(size_t)r * instride4 + c];
    ushort4 h;
    h.x = f2h(v.x); h.y = f2h(v.y); h.z = f2h(v.z); h.w = f2h(v.w);
    ((ushort4*)out)[i] = h;
}

__global__ void transpose_k(const float* __restrict__ in, float* __restrict__ out)
{
    __shared__ float tile[32][33];
    const int bx = blockIdx.x * 32, by = blockIdx.y * 32;
    const int tx = threadIdx.x, ty = threadIdx.y;   // (32,8)
#pragma unroll
    for (int i = 0; i < 32; i += 8)
        tile[ty + i][tx] = in[(size_t)(by + ty + i) * 1024 + bx + tx];
    __syncthreads();
#pragma unroll
    for (int i = 0; i < 32; i += 8)
        out[(size_t)(bx + ty + i) * 1024 + by + tx] = tile[tx][ty + i];
}

__global__ __launch_bounds__(256) void add_bias_k(
    const float* __restrict__ a, const float* __restrict__ b, float* __restrict__ o, int n)
{
    const int i = blockIdx.x * 256 + threadIdx.x;
    if (i < n) o[i] = a[i] + b[i];
}

__global__ __launch_bounds__(256) void finalize_k(
    const float* __restrict__ out_full, const float* __restrict__ c_buf,
    float* __restrict__ hT, float* __restrict__ cT)
{
    const int idx = blockIdx.x * 256 + threadIdx.x;
    const int b = idx >> 10, j = idx & 1023;
    hT[idx] = out_full[(size_t)b * T_ * H_ + (size_t)(T_ - 1) * H_ + j];
    cT[idx] = c_buf[idx];
}

extern "C" void kernel_launch(void* const* d_in, const int* in_sizes, int n_in,
                              void* d_out, int out_size, void* d_ws, size_t ws_size,
                              hipStream_t stream) {
    const float* target = (const float*)d_in[0];
    const float* h0     = (const float*)d_in[1];
    const float* c0     = (const float*)d_in[2];
    const float* ctx    = (const float*)d_in[3];
    const float* mask   = (const float*)d_in[4];
    const float* W_ih   = (const float*)d_in[5];
    const float* b_ih   = (const float*)d_in[6];
    const float* W_hh   = (const float*)d_in[7];
    const float* b_hh   = (const float*)d_in[8];
    const float* W_in   = (const float*)d_in[9];
    const float* W_ctx  = (const float*)d_in[10];
    const float* W_out  = (const float*)d_in[11];

    float* out = (float*)d_out;
    float* hT  = out + (size_t)B_ * T_ * H_;
    float* cT  = hT + (size_t)B_ * H_;

    // ---- workspace layout ----
    char* p = (char*)d_ws;
    ushort* E_h   = (ushort*)p;            p += 8388608ull * 2;    // 16.78 MB fp16
    float*  xW    = (float*)p;             p += 8388608ull * 4;    // 33.55 MB
    ushort* Gt16  = (ushort*)p;            p += 8388608ull * 2;    // 16.78 MB fp16
    ushort* Whh16 = (ushort*)p;            p += 4194304ull * 2;    // 8.39 MB fp16
    ushort* Woi16 = (ushort*)p;            p += 1048576ull * 2;    // 2.10 MB fp16
    float*  bias_sum = (float*)p;          p += 4096ull * 4;
    float*  c_buf = (float*)p;             p += 65536ull * 4;
    ushort* hy16  = (ushort*)p;            p += 65536ull * 2;
    ushort* hc16  = (ushort*)p;            p += 65536ull * 2;
    float*  sc_raw = (float*)p;            p += 8192ull * 4;
    ushort* dcslot = (ushort*)p;           p += 8388608ull * 2;    // dc16, later tgt16
    ushort* trans  = (ushort*)p;           p += 20971520ull * 2;   // 41.9 MB transient

    ushort* dc16   = dcslot;
    // transient phase A: ctx fp16 + W_ctx fp16
    ushort* ctx16  = trans;                            // 16,777,216
    ushort* Wctx16 = trans + 16777216;                 // 2,097,152
    // transient phase B: WinT_f + WinT16 + Wo1_16 + Wo2_16
    float*  WinT_f = (float*)trans;                    // 1,048,576 f (2,097,152 u-slots)
    ushort* WinT16 = trans + 2097152;
    ushort* Wo1_16 = trans + 3145728;
    ushort* Wo2_16 = trans + 4194304;
    // transient phase C: tgt16 (dc slot) + Wih16 (trans)
    ushort* tgt16  = dcslot;
    ushort* Wih16  = trans;

    // ---- preamble ----
    add_bias_k<<<16, 256, 0, stream>>>(b_ih, b_hh, bias_sum, 4 * H_);
    cvt1h_k<<<4096, 256, 0, stream>>>(W_hh, Whh16, 1048576);

    // dc16 = ctx @ W_ctx^T (fp16)
    cvt1h_k<<<16384, 256, 0, stream>>>(ctx, ctx16, 4194304);
    cvt1h_k<<<2048, 256, 0, stream>>>(W_ctx, Wctx16, 524288);
    gemm_16<4, 4><<<dim3(8, 64), 256, 0, stream>>>(
        ctx16, 2048, Wctx16, 2048, 2048, 1024,
        nullptr, dc16, nullptr, 0, 0, 0);

    // WinT, Woi16 = Wo2@W_in, E = dc@W_in (fp16), Gt[b] = Wo1 @ dc[b]^T (fp16)
    transpose_k<<<dim3(32, 32), dim3(32, 8), 0, stream>>>(W_in, WinT_f);
    cvt1h_k<<<1024, 256, 0, stream>>>(WinT_f, WinT16, 262144);
    cvt1hs_k<<<1024, 256, 0, stream>>>(W_out, 512, 256, Wo1_16, 262144);
    cvt1hs_k<<<1024, 256, 0, stream>>>(W_out + 1024, 512, 256, Wo2_16, 262144);
    gemm_16<4, 4><<<dim3(8, 8), 256, 0, stream>>>(
        Wo2_16, 1024, WinT16, 1024, 1024, 1024,
        nullptr, Woi16, nullptr, 0, 0, 0);
    gemm_16<4, 4><<<dim3(8, 64), 256, 0, stream>>>(
        dc16, 1024, WinT16, 1024, 1024, 1024,
        nullptr, E_h, nullptr, 0, 0, 0);
    gemm_16<4, 4><<<dim3(1, 8, 64), 256, 0, stream>>>(
        Wo1_16, 1024, dc16, 1024, 1024, 128,
        nullptr, Gt16, nullptr, 0, 131072, 131072);

    // xW = target @ W_ih^T + bias (dc dead now)
    cvt1h_k<<<2048, 256, 0, stream>>>(target, tgt16, 524288);
    cvt1h_k<<<4096, 256, 0, stream>>>(W_ih, Wih16, 1048576);
    gemm_16<4, 4><<<dim3(32, 16), 256, 0, stream>>>(
        tgt16, 1024, Wih16, 1024, 1024, 4096,
        xW, nullptr, bias_sum, 0, 0, 0);

    // loop state
    cvt1h_k<<<64, 256, 0, stream>>>(h0, hc16, 16384);
    hipMemcpyAsync(c_buf, c0, sizeof(float) * B_ * H_, hipMemcpyDeviceToDevice, stream);

    for (int t = 0; t < T_; ++t) {
        gates_cell<<<dim3(64, 4), 256, 0, stream>>>(
            hc16, Whh16, xW + (size_t)t * 4096, c_buf, hy16);
        scores_k<<<dim3(64, 4), 256, 0, stream>>>(E_h, hy16, mask, sc_raw);
        outg_k<<<dim3(64, 4), 256, 0, stream>>>(
            sc_raw, Gt16, hy16, Woi16,
            out + (size_t)t * H_, hc16);
    }

    finalize_k<<<256, 256, 0, stream>>>(out, c_buf, hT, cT);
}